// Round 12
// baseline (425.417 us; speedup 1.0000x reference)
//
#include <hip/hip_runtime.h>
#include <stdint.h>
#include <math.h>

#define GROUP 128
#define ZP 8
#define BM 256
#define BN 256
#define BK 32

typedef short short8 __attribute__((ext_vector_type(8)));   // 8 x bf16 bits
typedef float floatx4 __attribute__((ext_vector_type(4)));

typedef __attribute__((address_space(3))) void lds_void;
typedef const __attribute__((address_space(1))) void gbl_void;
#define GLOAD_LDS16(g, l) \
  __builtin_amdgcn_global_load_lds((gbl_void*)(g), (lds_void*)(l), 16, 0, 0)

#define VMCNT(n) asm volatile("s_waitcnt vmcnt(" #n ")" ::: "memory")
#define LGKM0()  asm volatile("s_waitcnt lgkmcnt(0)" ::: "memory")
#define BAR()    __builtin_amdgcn_s_barrier()
#define SCHEDB() __builtin_amdgcn_sched_barrier(0)

__device__ __forceinline__ ushort f2bf(float f) {  // round-to-nearest-even
    union { float f; uint32_t i; } v; v.f = f;
    uint32_t r = v.i + 0x7FFF + ((v.i >> 16) & 1);
    return (ushort)(r >> 16);
}

// ---------------------------------------------------------------------------
// Dequant + transpose: wt[n][k] = bf16((q[k][n] - 8) * scale_f32[k/128][n])
// ---------------------------------------------------------------------------
__global__ __launch_bounds__(256) void dequant_t_kernel(
    const int* __restrict__ q, const float* __restrict__ scale,
    ushort* __restrict__ wt, int K, int N)
{
    __shared__ ushort T[64 * 68];
    const int t  = threadIdx.x;
    const int k0 = blockIdx.x * 64;
    const int n0 = blockIdx.y * 64;
    const int g  = k0 / GROUP;
    const int c  = (t & 15) * 4;
    const int r0 = (t >> 4);

    const float4 s = *reinterpret_cast<const float4*>(&scale[(size_t)g * N + n0 + c]);

#pragma unroll
    for (int j = 0; j < 4; ++j) {
        const int r = r0 + j * 16;
        const int4 qv = *reinterpret_cast<const int4*>(&q[(size_t)(k0 + r) * N + n0 + c]);
        T[(c + 0) * 68 + r] = f2bf((float)(qv.x - ZP) * s.x);
        T[(c + 1) * 68 + r] = f2bf((float)(qv.y - ZP) * s.y);
        T[(c + 2) * 68 + r] = f2bf((float)(qv.z - ZP) * s.z);
        T[(c + 3) * 68 + r] = f2bf((float)(qv.w - ZP) * s.w);
    }
    __syncthreads();
#pragma unroll
    for (int j = 0; j < 4; ++j) {
        const int nn = r0 + j * 16;
        const int kk = c;
        const uint2 v = *reinterpret_cast<const uint2*>(&T[nn * 68 + kk]);
        *reinterpret_cast<uint2*>(&wt[(size_t)(n0 + nn) * K + k0 + kk]) = v;
    }
}

// ---------------------------------------------------------------------------
// GEMM: A fp32 [M][K] (converted in-kernel) x Wt bf16 [N][K] -> out fp32.
// 256x256 tile, BK=32, 8 waves (2Mx4N), per-wave 128x64 (acc 8x4 frags),
// 16x16x32 MFMA, round-7-validated swizzle/fragment pattern (0 conflicts).
// 4-slot ring. Ledger:
//   window T: issue A-fp32(T+1) [4 vm, to regs] + B-gload_lds(T+2) [2 vm];
//   compute tile T (12 ds_read, 32 MFMA, setprio);
//   boundary: vmcnt(2) -> retires B(T+1) (oldest, issued last window; robust
//   to intra-window reorder) + A(T+1) (also compiler reg-dep guarded);
//   cvt + ds_write A(T+1) into slot (T+1)&3 (disjoint from slot T reads and
//   from B DMA region); lgkm0; BAR.  Tail: window NT-2 uses vmcnt(0).
// Slot-reuse separation >= 1 full window everywhere.
// ---------------------------------------------------------------------------
__global__ __launch_bounds__(512, 2) void gemm256_fused_kernel(
    const float* __restrict__ Af, const ushort* __restrict__ Wt,
    float* __restrict__ out, int M, int N, int K)
{
    __shared__ ushort smem[4 * 16384];   // 4 slots x 32 KiB = 128 KiB

    const int bid = blockIdx.x;
    const int nwg = gridDim.x;
    int wg = bid;
    if ((nwg & 7) == 0) {                // bijective XCD swizzle
        const int cpx = nwg >> 3;
        wg = (bid & 7) * cpx + (bid >> 3);
    }
    const int ntn = N / BN;
    const int m0 = (wg / ntn) * BM;
    const int n0 = (wg % ntn) * BN;

    const int t    = threadIdx.x;
    const int lane = t & 63;
    const int w    = t >> 6;
    const int wm   = w >> 2;             // 2 (M) x 4 (N) wave grid
    const int wn   = w & 3;
    const int NT   = K / BK;

    // Staging geometry: statement s covers row r = s*128 + (t>>2); thread t
    // owns 16B chunk j = (t&3) ^ ((r>>1)&3) (pre-swizzled source, linear dst).
    const float*  paf[2]; const ushort* pb[2];
    int dstA[2], dstB[2];
#pragma unroll
    for (int s = 0; s < 2; ++s) {
        const int r = s * 128 + (t >> 2);
        const int j = (t & 3) ^ ((r >> 1) & 3);
        paf[s] = Af + (size_t)(m0 + r) * K + j * 8;   // fp32 source (8 elems)
        pb[s]  = Wt + (size_t)(n0 + r) * K + j * 8;   // bf16 source (16B)
        dstA[s] = s * 8192 + t * 16;                  // byte offsets in slot
        dstB[s] = 16384 + s * 8192 + t * 16;
    }

    // Fragment read offsets: aoff[i] = aoff0 + i*1024 (swizzle XOR is
    // invariant under +16-row steps), boff[j] = boff0 + j*1024.
    const int sw    = (((lane & 15) >> 1) & 3) << 4;
    const int aoff0 = (wm * 128 + (lane & 15)) * 64 + (((lane >> 4) << 4) ^ sw);
    const int boff0 = 16384 + (wn * 64 + (lane & 15)) * 64 + (((lane >> 4) << 4) ^ sw);

    floatx4 acc[8][4];
#pragma unroll
    for (int i = 0; i < 8; ++i)
#pragma unroll
        for (int j = 0; j < 4; ++j) acc[i][j] = floatx4{0.f, 0.f, 0.f, 0.f};

    // A-convert helper: 8 fp32 -> 16B bf16 written to LDS.
    auto cvt_write = [&](char* sa, int s, const float4& v0, const float4& v1)
        __attribute__((always_inline)) {
        ushort o[8] __attribute__((aligned(16)));
        o[0] = f2bf(v0.x); o[1] = f2bf(v0.y); o[2] = f2bf(v0.z); o[3] = f2bf(v0.w);
        o[4] = f2bf(v1.x); o[5] = f2bf(v1.y); o[6] = f2bf(v1.z); o[7] = f2bf(v1.w);
        *reinterpret_cast<uint4*>(sa + dstA[s]) = *reinterpret_cast<const uint4*>(o);
    };

    // Compute one tile: 12 ds_read_b128 + 32 MFMA (no sync).
    auto compute = [&](int T) __attribute__((always_inline)) {
        const char* sb = (const char*)smem + (T & 3) * 32768;
        short8 af[8], bf[4];
#pragma unroll
        for (int i = 0; i < 8; ++i)
            af[i] = *reinterpret_cast<const short8*>(sb + aoff0 + i * 1024);
#pragma unroll
        for (int j = 0; j < 4; ++j)
            bf[j] = *reinterpret_cast<const short8*>(sb + boff0 + j * 1024);
        __builtin_amdgcn_s_setprio(1);
#pragma unroll
        for (int i = 0; i < 8; ++i)
#pragma unroll
            for (int j = 0; j < 4; ++j)
                acc[i][j] = __builtin_amdgcn_mfma_f32_16x16x32_bf16(af[i], bf[j], acc[i][j], 0, 0, 0);
        __builtin_amdgcn_s_setprio(0);
    };

    // Prologue: A0 fp32 loads (4 vm), B0+B1 stages (4 vm).
    float4 a00 = *reinterpret_cast<const float4*>(paf[0]);
    float4 a01 = *reinterpret_cast<const float4*>(paf[0] + 4);
    float4 a10 = *reinterpret_cast<const float4*>(paf[1]);
    float4 a11 = *reinterpret_cast<const float4*>(paf[1] + 4);
    GLOAD_LDS16(pb[0], (char*)smem + dstB[0]);
    GLOAD_LDS16(pb[1], (char*)smem + dstB[1]);
    GLOAD_LDS16(pb[0] + 32, (char*)smem + 32768 + dstB[0]);
    GLOAD_LDS16(pb[1] + 32, (char*)smem + 32768 + dstB[1]);
    VMCNT(2);                            // A0 + B0 retired; B1 in flight
    cvt_write((char*)smem, 0, a00, a01);
    cvt_write((char*)smem, 1, a10, a11);
    LGKM0();
    BAR();

    // Main loop: windows T = 0 .. NT-3 (issues A(T+1) and B(T+2)).
    for (int T = 0; T <= NT - 3; ++T) {
        const int ka = (T + 1) * 32;
        a00 = *reinterpret_cast<const float4*>(paf[0] + ka);
        a01 = *reinterpret_cast<const float4*>(paf[0] + ka + 4);
        a10 = *reinterpret_cast<const float4*>(paf[1] + ka);
        a11 = *reinterpret_cast<const float4*>(paf[1] + ka + 4);
        char* sd = (char*)smem + ((T + 2) & 3) * 32768;
        GLOAD_LDS16(pb[0] + (T + 2) * 32, sd + dstB[0]);
        GLOAD_LDS16(pb[1] + (T + 2) * 32, sd + dstB[1]);

        compute(T);

        VMCNT(2);                        // B(T+1) [oldest] + A(T+1) retired
        char* sa = (char*)smem + ((T + 1) & 3) * 32768;
        cvt_write(sa, 0, a00, a01);
        cvt_write(sa, 1, a10, a11);
        LGKM0();                         // ds_writes (and reads) drained...
        SCHEDB();                        // ...pinned before the barrier
        BAR();
    }

    // Window NT-2: issue A(NT-1) only; boundary vmcnt(0).
    {
        const int ka = (NT - 1) * 32;
        a00 = *reinterpret_cast<const float4*>(paf[0] + ka);
        a01 = *reinterpret_cast<const float4*>(paf[0] + ka + 4);
        a10 = *reinterpret_cast<const float4*>(paf[1] + ka);
        a11 = *reinterpret_cast<const float4*>(paf[1] + ka + 4);

        compute(NT - 2);

        VMCNT(0);                        // B(NT-1) + A(NT-1) retired
        char* sa = (char*)smem + ((NT - 1) & 3) * 32768;
        cvt_write(sa, 0, a00, a01);
        cvt_write(sa, 1, a10, a11);
        LGKM0();
        SCHEDB();
        BAR();
    }
    compute(NT - 1);

    // Epilogue: D col = lane&15, row = 4*(lane>>4)+reg  (fp32 out)
    const int orow0 = m0 + wm * 128 + (lane >> 4) * 4;
    const int ocol0 = n0 + wn * 64 + (lane & 15);
#pragma unroll
    for (int i = 0; i < 8; ++i)
#pragma unroll
        for (int j = 0; j < 4; ++j)
#pragma unroll
            for (int r = 0; r < 4; ++r)
                out[(size_t)(orow0 + i * 16 + r) * N + ocol0 + j * 16] = acc[i][j][r];
}

// ---------------------------------------------------------------------------
// Last-resort naive VALU path (no workspace / odd shapes): correct, slow.
// ---------------------------------------------------------------------------
#define MR 16
__global__ __launch_bounds__(256) void naive_kernel(
    const float* __restrict__ x, const int* __restrict__ q,
    const float* __restrict__ sc, float* __restrict__ out,
    int M, int N, int K)
{
    const int n  = blockIdx.x * 256 + threadIdx.x;
    const int m0 = blockIdx.y * MR;
    float acc[MR];
#pragma unroll
    for (int i = 0; i < MR; ++i) acc[i] = 0.f;
    for (int k = 0; k < K; ++k) {
        const float s = sc[(size_t)(k / GROUP) * N + n];
        const float w = (float)(q[(size_t)k * N + n] - ZP) * s;
#pragma unroll
        for (int i = 0; i < MR; ++i)
            acc[i] = fmaf(x[(size_t)(m0 + i) * K + k], w, acc[i]);
    }
#pragma unroll
    for (int i = 0; i < MR; ++i)
        out[(size_t)(m0 + i) * N + n] = acc[i];
}

extern "C" void kernel_launch(void* const* d_in, const int* in_sizes, int n_in,
                              void* d_out, int out_size, void* d_ws, size_t ws_size,
                              hipStream_t stream) {
    const float* x  = (const float*)d_in[0];
    const int*   q  = (const int*)d_in[1];
    const float* sc = (const float*)d_in[2];
    float*       o  = (float*)d_out;

    int M = 8192, K = 4096, N = 4096;
    if (!((long long)in_sizes[0] == (long long)M * K &&
          (long long)in_sizes[1] == (long long)K * N &&
          (long long)out_size    == (long long)M * N)) {
        const double S0 = (double)in_sizes[0], S1 = (double)in_sizes[1];
        K = (int)llround(sqrt(S0 * S1 / (double)out_size));
        N = in_sizes[1] / K;
        M = in_sizes[0] / K;
    }

    const size_t wt_bytes = (size_t)N * K * 2;

    const bool ok = (M % BM == 0) && (N % BN == 0) && (K % BK == 0) &&
                    (K / BK >= 4) && (N % 64 == 0) && (K % 64 == 0) &&
                    (K % GROUP == 0) && (ws_size >= wt_bytes);

    if (ok) {
        ushort* wt = (ushort*)d_ws;
        dequant_t_kernel<<<dim3(K / 64, N / 64), 256, 0, stream>>>(q, sc, wt, K, N);
        const int ngemm = (M / BM) * (N / BN);
        gemm256_fused_kernel<<<dim3(ngemm), 512, 0, stream>>>(x, wt, o, M, N, K);
    } else {
        naive_kernel<<<dim3(N / 256, M / MR), 256, 0, stream>>>(x, q, sc, o, M, N, K);
    }
}

// Round 13
// 291.524 us; speedup vs baseline: 1.4593x; 1.4593x over previous
//
#include <hip/hip_runtime.h>
#include <stdint.h>
#include <math.h>

#define GROUP 128
#define ZP 8
#define BM 256
#define BN 256
#define BK 32

typedef short short8 __attribute__((ext_vector_type(8)));   // 8 x bf16 bits
typedef float floatx4 __attribute__((ext_vector_type(4)));

typedef __attribute__((address_space(3))) void lds_void;
typedef const __attribute__((address_space(1))) void gbl_void;
#define GLOAD_LDS16(g, l) \
  __builtin_amdgcn_global_load_lds((gbl_void*)(g), (lds_void*)(l), 16, 0, 0)

#define VMCNT(n) asm volatile("s_waitcnt vmcnt(" #n ")" ::: "memory")
#define LGKM0()  asm volatile("s_waitcnt lgkmcnt(0)" ::: "memory")
#define BAR()    __builtin_amdgcn_s_barrier()
#define SCHEDB() __builtin_amdgcn_sched_barrier(0)

__device__ __forceinline__ ushort f2bf(float f) {  // round-to-nearest-even
    union { float f; uint32_t i; } v; v.f = f;
    uint32_t r = v.i + 0x7FFF + ((v.i >> 16) & 1);
    return (ushort)(r >> 16);
}

// ---------------------------------------------------------------------------
// Merged prepass (both memory-bound; one launch):
//   blocks [0, ndeq):        dequant+transpose  wt[n][k] = bf16((q-8)*s)
//   blocks [ndeq, gridDim):  x fp32 -> bf16 (grid-stride, 8 elems/thread)
// Both parts byte-identical math to the round-5/7-validated kernels.
// ---------------------------------------------------------------------------
__global__ __launch_bounds__(256) void prep_kernel(
    const float* __restrict__ x, const int* __restrict__ q,
    const float* __restrict__ scale, ushort* __restrict__ xb,
    ushort* __restrict__ wt, int K, int N, size_t total8, int ndeq)
{
    __shared__ ushort T[64 * 68];
    const int t = threadIdx.x;

    if ((int)blockIdx.x < ndeq) {
        const int ktiles = K / 64;
        const int k0 = (blockIdx.x % ktiles) * 64;
        const int n0 = (blockIdx.x / ktiles) * 64;
        const int g  = k0 / GROUP;
        const int c  = (t & 15) * 4;
        const int r0 = (t >> 4);

        const float4 s = *reinterpret_cast<const float4*>(&scale[(size_t)g * N + n0 + c]);

#pragma unroll
        for (int j = 0; j < 4; ++j) {
            const int r = r0 + j * 16;
            const int4 qv = *reinterpret_cast<const int4*>(&q[(size_t)(k0 + r) * N + n0 + c]);
            T[(c + 0) * 68 + r] = f2bf((float)(qv.x - ZP) * s.x);
            T[(c + 1) * 68 + r] = f2bf((float)(qv.y - ZP) * s.y);
            T[(c + 2) * 68 + r] = f2bf((float)(qv.z - ZP) * s.z);
            T[(c + 3) * 68 + r] = f2bf((float)(qv.w - ZP) * s.w);
        }
        __syncthreads();
#pragma unroll
        for (int j = 0; j < 4; ++j) {
            const int nn = r0 + j * 16;
            const int kk = c;
            const uint2 v = *reinterpret_cast<const uint2*>(&T[nn * 68 + kk]);
            *reinterpret_cast<uint2*>(&wt[(size_t)(n0 + nn) * K + k0 + kk]) = v;
        }
    } else {
        const size_t nblk   = (size_t)(gridDim.x - ndeq);
        const size_t stride = nblk * 256;
        for (size_t id = (size_t)(blockIdx.x - ndeq) * 256 + t; id < total8; id += stride) {
            const float4 a = *reinterpret_cast<const float4*>(x + id * 8);
            const float4 b = *reinterpret_cast<const float4*>(x + id * 8 + 4);
            ushort o[8] __attribute__((aligned(16)));
            o[0] = f2bf(a.x); o[1] = f2bf(a.y); o[2] = f2bf(a.z); o[3] = f2bf(a.w);
            o[4] = f2bf(b.x); o[5] = f2bf(b.y); o[6] = f2bf(b.z); o[7] = f2bf(b.w);
            *reinterpret_cast<uint4*>(xb + id * 8) = *reinterpret_cast<const uint4*>(o);
        }
    }
}

// ---------------------------------------------------------------------------
// GEMM: A bf16 [M][K] x Wt bf16 [N][K] -> out fp32 [M][N]
// 256x256 tile, BK=32, 8 waves (2Mx4N), per-wave 128x64 (acc 8x4 frags),
// 16x16x32 MFMA. ROUND-7-VALIDATED kernel, byte-for-byte: 4-slot ring,
// stage tile T+3 during window T, vmcnt(8) boundary, tail vmcnt(4)/(0),
// XOR chunk swizzle both-sides (measured 0 bank conflicts), setprio(1)
// around the MFMA cluster. Measured: 248 us, MfmaUtil 49%, VGPR 100.
// ---------------------------------------------------------------------------
__global__ __launch_bounds__(512, 2) void gemm256_ring_kernel(
    const ushort* __restrict__ Ab, const ushort* __restrict__ Wt,
    float* __restrict__ out, int M, int N, int K)
{
    __shared__ ushort smem[4 * 16384];   // 4 slots x 32 KiB = 128 KiB

    const int bid = blockIdx.x;
    const int nwg = gridDim.x;
    int wg = bid;
    if ((nwg & 7) == 0) {                // bijective XCD swizzle
        const int cpx = nwg >> 3;
        wg = (bid & 7) * cpx + (bid >> 3);
    }
    const int ntn = N / BN;
    const int m0 = (wg / ntn) * BM;
    const int n0 = (wg % ntn) * BN;

    const int t    = threadIdx.x;
    const int lane = t & 63;
    const int w    = t >> 6;
    const int wm   = w >> 2;             // 2 (M) x 4 (N) wave grid
    const int wn   = w & 3;
    const int NT   = K / BK;

    // Staging: statement s covers rows s*128 + (t>>2); thread t stages the
    // 16B chunk j = (t&3) ^ ((row>>1)&3) of the row's 64B (pre-swizzled
    // global source, linear LDS destination).
    const ushort* pa[2]; const ushort* pb[2];
    int dstA[2], dstB[2];
#pragma unroll
    for (int s = 0; s < 2; ++s) {
        const int r = s * 128 + (t >> 2);
        const int j = (t & 3) ^ ((r >> 1) & 3);
        pa[s] = Ab + (size_t)(m0 + r) * K + j * 8;
        pb[s] = Wt + (size_t)(n0 + r) * K + j * 8;
        dstA[s] = s * 8192 + t * 16;            // byte offsets within slot
        dstB[s] = 16384 + s * 8192 + t * 16;
    }

    // Fragment read byte-offsets within a slot (swizzled read).
    int aoff[8], boff[4];
#pragma unroll
    for (int i = 0; i < 8; ++i) {
        const int r = wm * 128 + i * 16 + (lane & 15);
        aoff[i] = r * 64 + (((lane >> 4) ^ ((r >> 1) & 3)) << 4);
    }
#pragma unroll
    for (int j = 0; j < 4; ++j) {
        const int r = wn * 64 + j * 16 + (lane & 15);
        boff[j] = 16384 + r * 64 + (((lane >> 4) ^ ((r >> 1) & 3)) << 4);
    }

    floatx4 acc[8][4];
#pragma unroll
    for (int i = 0; i < 8; ++i)
#pragma unroll
        for (int j = 0; j < 4; ++j) acc[i][j] = floatx4{0.f, 0.f, 0.f, 0.f};

    // Prologue: stage tiles 0,1,2 into slots 0,1,2 (issue order = tile order).
#pragma unroll
    for (int U = 0; U < 3; ++U) {
        char* sb = (char*)smem + U * 32768;
        GLOAD_LDS16(pa[0] + U * 32, sb + dstA[0]);
        GLOAD_LDS16(pa[1] + U * 32, sb + dstA[1]);
        GLOAD_LDS16(pb[0] + U * 32, sb + dstB[0]);
        GLOAD_LDS16(pb[1] + U * 32, sb + dstB[1]);
    }
    VMCNT(8);                            // tile 0's 4 statements retired
    BAR();

    auto body = [&](int T, bool issue) __attribute__((always_inline)) {
        if (issue) {                     // stage tile T+3 into slot (T+3)&3
            char* sd = (char*)smem + ((T + 3) & 3) * 32768;
            const int ko = (T + 3) * 32;
            GLOAD_LDS16(pa[0] + ko, sd + dstA[0]);
            GLOAD_LDS16(pa[1] + ko, sd + dstA[1]);
            GLOAD_LDS16(pb[0] + ko, sd + dstB[0]);
            GLOAD_LDS16(pb[1] + ko, sd + dstB[1]);
        }
        const char* sb = (const char*)smem + (T & 3) * 32768;
        short8 af[8], bf[4];
#pragma unroll
        for (int i = 0; i < 8; ++i)
            af[i] = *reinterpret_cast<const short8*>(sb + aoff[i]);
#pragma unroll
        for (int j = 0; j < 4; ++j)
            bf[j] = *reinterpret_cast<const short8*>(sb + boff[j]);
        __builtin_amdgcn_s_setprio(1);
#pragma unroll
        for (int i = 0; i < 8; ++i)
#pragma unroll
            for (int j = 0; j < 4; ++j)
                acc[i][j] = __builtin_amdgcn_mfma_f32_16x16x32_bf16(af[i], bf[j], acc[i][j], 0, 0, 0);
        __builtin_amdgcn_s_setprio(0);
        LGKM0();                         // this wave's ds_reads drained...
        SCHEDB();                        // ...and pinned before the barrier
    };

    for (int T = 0; T + 3 < NT; ++T) {   // always issues (tile T+3)
        body(T, true);
        VMCNT(8);                        // oldest 4 (= tile T+1's stmts) retired
        BAR();
    }
    body(NT - 3, false); VMCNT(4); BAR();
    body(NT - 2, false); VMCNT(0); BAR();
    body(NT - 1, false);

    // Epilogue: D col = lane&15, row = 4*(lane>>4)+reg  (fp32 out)
    const int orow0 = m0 + wm * 128 + (lane >> 4) * 4;
    const int ocol0 = n0 + wn * 64 + (lane & 15);
#pragma unroll
    for (int i = 0; i < 8; ++i)
#pragma unroll
        for (int j = 0; j < 4; ++j)
#pragma unroll
            for (int r = 0; r < 4; ++r)
                out[(size_t)(orow0 + i * 16 + r) * N + ocol0 + j * 16] = acc[i][j][r];
}

// ---------------------------------------------------------------------------
// Last-resort naive VALU path (no workspace / odd shapes): correct, slow.
// ---------------------------------------------------------------------------
#define MR 16
__global__ __launch_bounds__(256) void naive_kernel(
    const float* __restrict__ x, const int* __restrict__ q,
    const float* __restrict__ sc, float* __restrict__ out,
    int M, int N, int K)
{
    const int n  = blockIdx.x * 256 + threadIdx.x;
    const int m0 = blockIdx.y * MR;
    float acc[MR];
#pragma unroll
    for (int i = 0; i < MR; ++i) acc[i] = 0.f;
    for (int k = 0; k < K; ++k) {
        const float s = sc[(size_t)(k / GROUP) * N + n];
        const float w = (float)(q[(size_t)k * N + n] - ZP) * s;
#pragma unroll
        for (int i = 0; i < MR; ++i)
            acc[i] = fmaf(x[(size_t)(m0 + i) * K + k], w, acc[i]);
    }
#pragma unroll
    for (int i = 0; i < MR; ++i)
        out[(size_t)(m0 + i) * N + n] = acc[i];
}

extern "C" void kernel_launch(void* const* d_in, const int* in_sizes, int n_in,
                              void* d_out, int out_size, void* d_ws, size_t ws_size,
                              hipStream_t stream) {
    const float* x  = (const float*)d_in[0];
    const int*   q  = (const int*)d_in[1];
    const float* sc = (const float*)d_in[2];
    float*       o  = (float*)d_out;

    int M = 8192, K = 4096, N = 4096;
    if (!((long long)in_sizes[0] == (long long)M * K &&
          (long long)in_sizes[1] == (long long)K * N &&
          (long long)out_size    == (long long)M * N)) {
        const double S0 = (double)in_sizes[0], S1 = (double)in_sizes[1];
        K = (int)llround(sqrt(S0 * S1 / (double)out_size));
        N = in_sizes[1] / K;
        M = in_sizes[0] / K;
    }

    const size_t xb_bytes = (size_t)M * K * 2;
    const size_t wt_bytes = (size_t)N * K * 2;

    const bool ok = (M % BM == 0) && (N % BN == 0) && (K % BK == 0) &&
                    (K / BK >= 4) && (N % 64 == 0) && (K % 64 == 0) &&
                    (K % GROUP == 0) && (ws_size >= xb_bytes + wt_bytes);

    if (ok) {
        ushort* xb = (ushort*)d_ws;
        ushort* wt = (ushort*)((char*)d_ws + xb_bytes);
        const int ndeq = (K / 64) * (N / 64);
        prep_kernel<<<dim3(ndeq + 2048), 256, 0, stream>>>(
            x, q, sc, xb, wt, K, N, (size_t)M * K / 8, ndeq);
        const int ngemm = (M / BM) * (N / BN);
        gemm256_ring_kernel<<<dim3(ngemm), 512, 0, stream>>>(xb, wt, o, M, N, K);
    } else {
        naive_kernel<<<dim3(N / 256, M / MR), 256, 0, stream>>>(x, q, sc, o, M, N, K);
    }
}

// Round 15
// 285.201 us; speedup vs baseline: 1.4916x; 1.0222x over previous
//
#include <hip/hip_runtime.h>
#include <stdint.h>
#include <math.h>

#define GROUP 128
#define ZP 8
#define BM 256
#define BN 256
#define BK 32

typedef short short8 __attribute__((ext_vector_type(8)));   // 8 x bf16 bits
typedef float floatx4 __attribute__((ext_vector_type(4)));

typedef __attribute__((address_space(3))) void lds_void;
typedef const __attribute__((address_space(1))) void gbl_void;
#define GLOAD_LDS16(g, l) \
  __builtin_amdgcn_global_load_lds((gbl_void*)(g), (lds_void*)(l), 16, 0, 0)

#define VMCNT(n) asm volatile("s_waitcnt vmcnt(" #n ")" ::: "memory")
#define LGKM0()  asm volatile("s_waitcnt lgkmcnt(0)" ::: "memory")
#define BAR()    __builtin_amdgcn_s_barrier()
#define SCHEDB() __builtin_amdgcn_sched_barrier(0)

__device__ __forceinline__ ushort f2bf(float f) {  // round-to-nearest-even
    union { float f; uint32_t i; } v; v.f = f;
    uint32_t r = v.i + 0x7FFF + ((v.i >> 16) & 1);
    return (ushort)(r >> 16);
}

// ---------------------------------------------------------------------------
// Merged prepass (both memory-bound; one launch):
//   blocks [0, ndeq):        dequant+transpose  wt[n][k] = bf16((q-8)*s)
//   blocks [ndeq, gridDim):  x fp32 -> bf16 (grid-stride, 8 elems/thread)
// ---------------------------------------------------------------------------
__global__ __launch_bounds__(256) void prep_kernel(
    const float* __restrict__ x, const int* __restrict__ q,
    const float* __restrict__ scale, ushort* __restrict__ xb,
    ushort* __restrict__ wt, int K, int N, size_t total8, int ndeq)
{
    __shared__ ushort T[64 * 68];
    const int t = threadIdx.x;

    if ((int)blockIdx.x < ndeq) {
        const int ktiles = K / 64;
        const int k0 = (blockIdx.x % ktiles) * 64;
        const int n0 = (blockIdx.x / ktiles) * 64;
        const int g  = k0 / GROUP;
        const int c  = (t & 15) * 4;
        const int r0 = (t >> 4);

        const float4 s = *reinterpret_cast<const float4*>(&scale[(size_t)g * N + n0 + c]);

#pragma unroll
        for (int j = 0; j < 4; ++j) {
            const int r = r0 + j * 16;
            const int4 qv = *reinterpret_cast<const int4*>(&q[(size_t)(k0 + r) * N + n0 + c]);
            T[(c + 0) * 68 + r] = f2bf((float)(qv.x - ZP) * s.x);
            T[(c + 1) * 68 + r] = f2bf((float)(qv.y - ZP) * s.y);
            T[(c + 2) * 68 + r] = f2bf((float)(qv.z - ZP) * s.z);
            T[(c + 3) * 68 + r] = f2bf((float)(qv.w - ZP) * s.w);
        }
        __syncthreads();
#pragma unroll
        for (int j = 0; j < 4; ++j) {
            const int nn = r0 + j * 16;
            const int kk = c;
            const uint2 v = *reinterpret_cast<const uint2*>(&T[nn * 68 + kk]);
            *reinterpret_cast<uint2*>(&wt[(size_t)(n0 + nn) * K + k0 + kk]) = v;
        }
    } else {
        const size_t nblk   = (size_t)(gridDim.x - ndeq);
        const size_t stride = nblk * 256;
        for (size_t id = (size_t)(blockIdx.x - ndeq) * 256 + t; id < total8; id += stride) {
            const float4 a = *reinterpret_cast<const float4*>(x + id * 8);
            const float4 b = *reinterpret_cast<const float4*>(x + id * 8 + 4);
            ushort o[8] __attribute__((aligned(16)));
            o[0] = f2bf(a.x); o[1] = f2bf(a.y); o[2] = f2bf(a.z); o[3] = f2bf(a.w);
            o[4] = f2bf(b.x); o[5] = f2bf(b.y); o[6] = f2bf(b.z); o[7] = f2bf(b.w);
            *reinterpret_cast<uint4*>(xb + id * 8) = *reinterpret_cast<const uint4*>(o);
        }
    }
}

// ---------------------------------------------------------------------------
// GEMM: A bf16 [M][K] x Wt bf16 [N][K] -> out fp32 [M][N]
// 256x256 tile, BK=32, 8 waves (2Mx4N), per-wave 128x64 (acc 8x4 frags),
// 16x16x32 MFMA, round-7-validated swizzle (0 conflicts).
// Cross-barrier fragment prefetch, CORRECTED ledger (vmcnt(4) boundaries):
//   A wave's pre-barrier read of frags(T+1) requires tile T+1 proven
//   GLOBALLY, i.e. retired by every wave's vmcnt BEFORE the entry barrier
//   of window T. Boundary vmcnt(4) retires tile T+1 (outstanding there =
//   {T+1, T+2} = 8 stmts) -> entry barrier globalizes it.  [Round-14's
//   vmcnt(8) only proved the reader's own DMA -> cross-wave race.]
//   window T: lgkm0;SCHEDB | stage T+3 | 32 MFMA (setprio) | SCHEDB
//             vmcnt(4) [retires T+2 for next window's prefetch]
//             read frags(T+1) [proven at entry barrier] | BAR
// vmcnt(4) drains stages issued a full window (~2300cyc) earlier -> free.
// Tail: NT-3 boundary vmcnt(0); last two windows barrier-free.
// ---------------------------------------------------------------------------
__global__ __launch_bounds__(512, 2) void gemm256_pipe_kernel(
    const ushort* __restrict__ Ab, const ushort* __restrict__ Wt,
    float* __restrict__ out, int M, int N, int K)
{
    __shared__ ushort smem[4 * 16384];   // 4 slots x 32 KiB = 128 KiB

    const int bid = blockIdx.x;
    const int nwg = gridDim.x;
    int wg = bid;
    if ((nwg & 7) == 0) {                // bijective XCD swizzle
        const int cpx = nwg >> 3;
        wg = (bid & 7) * cpx + (bid >> 3);
    }
    const int ntn = N / BN;
    const int m0 = (wg / ntn) * BM;
    const int n0 = (wg % ntn) * BN;

    const int t    = threadIdx.x;
    const int lane = t & 63;
    const int w    = t >> 6;
    const int wm   = w >> 2;             // 2 (M) x 4 (N) wave grid
    const int wn   = w & 3;
    const int NT   = K / BK;

    // Staging: statement s covers rows s*128 + (t>>2); thread t stages the
    // 16B chunk j = (t&3) ^ ((row>>1)&3) of the row's 64B (pre-swizzled
    // global source, linear LDS destination).
    const ushort* pa[2]; const ushort* pb[2];
    int dstA[2], dstB[2];
#pragma unroll
    for (int s = 0; s < 2; ++s) {
        const int r = s * 128 + (t >> 2);
        const int j = (t & 3) ^ ((r >> 1) & 3);
        pa[s] = Ab + (size_t)(m0 + r) * K + j * 8;
        pb[s] = Wt + (size_t)(n0 + r) * K + j * 8;
        dstA[s] = s * 8192 + t * 16;            // byte offsets within slot
        dstB[s] = 16384 + s * 8192 + t * 16;
    }

    // Fragment read byte-offsets within a slot (swizzled read).
    int aoff[8], boff[4];
#pragma unroll
    for (int i = 0; i < 8; ++i) {
        const int r = wm * 128 + i * 16 + (lane & 15);
        aoff[i] = r * 64 + (((lane >> 4) ^ ((r >> 1) & 3)) << 4);
    }
#pragma unroll
    for (int j = 0; j < 4; ++j) {
        const int r = wn * 64 + j * 16 + (lane & 15);
        boff[j] = 16384 + r * 64 + (((lane >> 4) ^ ((r >> 1) & 3)) << 4);
    }

    floatx4 acc[8][4];
#pragma unroll
    for (int i = 0; i < 8; ++i)
#pragma unroll
        for (int j = 0; j < 4; ++j) acc[i][j] = floatx4{0.f, 0.f, 0.f, 0.f};

    short8 af[8], bf[4];                 // fragment registers, live across BAR

    auto stage = [&](int Td) __attribute__((always_inline)) {
        char* sd = (char*)smem + (Td & 3) * 32768;
        const int ko = Td * 32;
        GLOAD_LDS16(pa[0] + ko, sd + dstA[0]);
        GLOAD_LDS16(pa[1] + ko, sd + dstA[1]);
        GLOAD_LDS16(pb[0] + ko, sd + dstB[0]);
        GLOAD_LDS16(pb[1] + ko, sd + dstB[1]);
    };
    auto read_frags = [&](int T) __attribute__((always_inline)) {
        const char* sb = (const char*)smem + (T & 3) * 32768;
#pragma unroll
        for (int i = 0; i < 8; ++i)
            af[i] = *reinterpret_cast<const short8*>(sb + aoff[i]);
#pragma unroll
        for (int j = 0; j < 4; ++j)
            bf[j] = *reinterpret_cast<const short8*>(sb + boff[j]);
    };
    auto mfma_all = [&]() __attribute__((always_inline)) {
        __builtin_amdgcn_s_setprio(1);
#pragma unroll
        for (int i = 0; i < 8; ++i)
#pragma unroll
            for (int j = 0; j < 4; ++j)
                acc[i][j] = __builtin_amdgcn_mfma_f32_16x16x32_bf16(af[i], bf[j], acc[i][j], 0, 0, 0);
        __builtin_amdgcn_s_setprio(0);
    };

    // Prologue: stage tiles 0,1,2; vmcnt(4) retires tiles 0 AND 1; barrier
    // globalizes; read frags(0) post-barrier (safe: tile 0 proven globally).
    stage(0); stage(1); stage(2);
    VMCNT(4);
    BAR();
    read_frags(0);

    for (int T = 0; T + 3 < NT; ++T) {
        LGKM0();                         // frags(T) arrived
        SCHEDB();                        // don't let MFMAs hoist above wait
        stage(T + 3);
        mfma_all();
        SCHEDB();
        VMCNT(4);                        // retires tile T+2 (globalized at next BAR)
        read_frags(T + 1);               // tile T+1: proven at entry barrier
        BAR();
    }
    // T = NT-3: no stage; vmcnt(0) proves tile NT-1 for next prefetch.
    LGKM0(); SCHEDB(); mfma_all(); SCHEDB();
    VMCNT(0); read_frags(NT - 2); BAR();
    // T = NT-2: tile NT-1 proven at entry barrier; no more writes -> no BAR.
    LGKM0(); SCHEDB(); mfma_all();
    read_frags(NT - 1);
    LGKM0(); SCHEDB(); mfma_all();       // T = NT-1

    // Epilogue: D col = lane&15, row = 4*(lane>>4)+reg  (fp32 out)
    const int orow0 = m0 + wm * 128 + (lane >> 4) * 4;
    const int ocol0 = n0 + wn * 64 + (lane & 15);
#pragma unroll
    for (int i = 0; i < 8; ++i)
#pragma unroll
        for (int j = 0; j < 4; ++j)
#pragma unroll
            for (int r = 0; r < 4; ++r)
                out[(size_t)(orow0 + i * 16 + r) * N + ocol0 + j * 16] = acc[i][j][r];
}

// ---------------------------------------------------------------------------
// Last-resort naive VALU path (no workspace / odd shapes): correct, slow.
// ---------------------------------------------------------------------------
#define MR 16
__global__ __launch_bounds__(256) void naive_kernel(
    const float* __restrict__ x, const int* __restrict__ q,
    const float* __restrict__ sc, float* __restrict__ out,
    int M, int N, int K)
{
    const int n  = blockIdx.x * 256 + threadIdx.x;
    const int m0 = blockIdx.y * MR;
    float acc[MR];
#pragma unroll
    for (int i = 0; i < MR; ++i) acc[i] = 0.f;
    for (int k = 0; k < K; ++k) {
        const float s = sc[(size_t)(k / GROUP) * N + n];
        const float w = (float)(q[(size_t)k * N + n] - ZP) * s;
#pragma unroll
        for (int i = 0; i < MR; ++i)
            acc[i] = fmaf(x[(size_t)(m0 + i) * K + k], w, acc[i]);
    }
#pragma unroll
    for (int i = 0; i < MR; ++i)
        out[(size_t)(m0 + i) * N + n] = acc[i];
}

extern "C" void kernel_launch(void* const* d_in, const int* in_sizes, int n_in,
                              void* d_out, int out_size, void* d_ws, size_t ws_size,
                              hipStream_t stream) {
    const float* x  = (const float*)d_in[0];
    const int*   q  = (const int*)d_in[1];
    const float* sc = (const float*)d_in[2];
    float*       o  = (float*)d_out;

    int M = 8192, K = 4096, N = 4096;
    if (!((long long)in_sizes[0] == (long long)M * K &&
          (long long)in_sizes[1] == (long long)K * N &&
          (long long)out_size    == (long long)M * N)) {
        const double S0 = (double)in_sizes[0], S1 = (double)in_sizes[1];
        K = (int)llround(sqrt(S0 * S1 / (double)out_size));
        N = in_sizes[1] / K;
        M = in_sizes[0] / K;
    }

    const size_t xb_bytes = (size_t)M * K * 2;
    const size_t wt_bytes = (size_t)N * K * 2;

    const bool ok = (M % BM == 0) && (N % BN == 0) && (K % BK == 0) &&
                    (K / BK >= 5) && (N % 64 == 0) && (K % 64 == 0) &&
                    (K % GROUP == 0) && (ws_size >= xb_bytes + wt_bytes);

    if (ok) {
        ushort* xb = (ushort*)d_ws;
        ushort* wt = (ushort*)((char*)d_ws + xb_bytes);
        const int ndeq = (K / 64) * (N / 64);
        prep_kernel<<<dim3(ndeq + 2048), 256, 0, stream>>>(
            x, q, sc, xb, wt, K, N, (size_t)M * K / 8, ndeq);
        const int ngemm = (M / BM) * (N / BN);
        gemm256_pipe_kernel<<<dim3(ngemm), 512, 0, stream>>>(xb, wt, o, M, N, K);
    } else {
        naive_kernel<<<dim3(N / 256, M / MR), 256, 0, stream>>>(x, q, sc, o, M, N, K);
    }
}

// Round 16
// 284.616 us; speedup vs baseline: 1.4947x; 1.0021x over previous
//
#include <hip/hip_runtime.h>
#include <stdint.h>
#include <math.h>

#define GROUP 128
#define ZP 8
#define BM 256
#define BN 256
#define BK 32

typedef short short8 __attribute__((ext_vector_type(8)));   // 8 x bf16 bits
typedef float floatx4 __attribute__((ext_vector_type(4)));

typedef __attribute__((address_space(3))) void lds_void;
typedef const __attribute__((address_space(1))) void gbl_void;
#define GLOAD_LDS16(g, l) \
  __builtin_amdgcn_global_load_lds((gbl_void*)(g), (lds_void*)(l), 16, 0, 0)

#define VMCNT(n) asm volatile("s_waitcnt vmcnt(" #n ")" ::: "memory")
#define LGKM0()  asm volatile("s_waitcnt lgkmcnt(0)" ::: "memory")
#define BAR()    __builtin_amdgcn_s_barrier()
#define SCHEDB() __builtin_amdgcn_sched_barrier(0)

__device__ __forceinline__ ushort f2bf(float f) {  // round-to-nearest-even
    union { float f; uint32_t i; } v; v.f = f;
    uint32_t r = v.i + 0x7FFF + ((v.i >> 16) & 1);
    return (ushort)(r >> 16);
}

// ---------------------------------------------------------------------------
// Merged prepass (both memory-bound; one launch):
//   blocks [0, ndeq):        dequant+transpose  wt[n][k] = bf16((q-8)*s)
//   blocks [ndeq, gridDim):  x fp32 -> bf16 (grid-stride, 8 elems/thread)
// ---------------------------------------------------------------------------
__global__ __launch_bounds__(256) void prep_kernel(
    const float* __restrict__ x, const int* __restrict__ q,
    const float* __restrict__ scale, ushort* __restrict__ xb,
    ushort* __restrict__ wt, int K, int N, size_t total8, int ndeq)
{
    __shared__ ushort T[64 * 68];
    const int t = threadIdx.x;

    if ((int)blockIdx.x < ndeq) {
        const int ktiles = K / 64;
        const int k0 = (blockIdx.x % ktiles) * 64;
        const int n0 = (blockIdx.x / ktiles) * 64;
        const int g  = k0 / GROUP;
        const int c  = (t & 15) * 4;
        const int r0 = (t >> 4);

        const float4 s = *reinterpret_cast<const float4*>(&scale[(size_t)g * N + n0 + c]);

#pragma unroll
        for (int j = 0; j < 4; ++j) {
            const int r = r0 + j * 16;
            const int4 qv = *reinterpret_cast<const int4*>(&q[(size_t)(k0 + r) * N + n0 + c]);
            T[(c + 0) * 68 + r] = f2bf((float)(qv.x - ZP) * s.x);
            T[(c + 1) * 68 + r] = f2bf((float)(qv.y - ZP) * s.y);
            T[(c + 2) * 68 + r] = f2bf((float)(qv.z - ZP) * s.z);
            T[(c + 3) * 68 + r] = f2bf((float)(qv.w - ZP) * s.w);
        }
        __syncthreads();
#pragma unroll
        for (int j = 0; j < 4; ++j) {
            const int nn = r0 + j * 16;
            const int kk = c;
            const uint2 v = *reinterpret_cast<const uint2*>(&T[nn * 68 + kk]);
            *reinterpret_cast<uint2*>(&wt[(size_t)(n0 + nn) * K + k0 + kk]) = v;
        }
    } else {
        const size_t nblk   = (size_t)(gridDim.x - ndeq);
        const size_t stride = nblk * 256;
        for (size_t id = (size_t)(blockIdx.x - ndeq) * 256 + t; id < total8; id += stride) {
            const float4 a = *reinterpret_cast<const float4*>(x + id * 8);
            const float4 b = *reinterpret_cast<const float4*>(x + id * 8 + 4);
            ushort o[8] __attribute__((aligned(16)));
            o[0] = f2bf(a.x); o[1] = f2bf(a.y); o[2] = f2bf(a.z); o[3] = f2bf(a.w);
            o[4] = f2bf(b.x); o[5] = f2bf(b.y); o[6] = f2bf(b.z); o[7] = f2bf(b.w);
            *reinterpret_cast<uint4*>(xb + id * 8) = *reinterpret_cast<const uint4*>(o);
        }
    }
}

// ---------------------------------------------------------------------------
// GEMM: A bf16 [M][K] x Wt bf16 [N][K] -> out fp32 [M][N]
// 256x256 tile, BK=32, 8 waves (2Mx4N), per-wave 128x64 (acc 8x4 frags),
// 16x16x32 MFMA, round-7-validated swizzle (0 conflicts).
// Round-15-validated vmcnt(4) ledger (tile T+1 proven globally at window-T
// ENTRY barrier). NEW this round: reads of frags(T+1) moved INSIDE the
// window — af[0..3] between the two MFMA half-bursts (overlaps rows 4-7
// issue; SSA rename reuses dying af[0..3] regs), af[4..7]+bf at window end
// BEFORE the vmcnt asm (was after: the clobber pinned them needlessly).
// Sync structure (stage slots, vmcnt depths, barriers) byte-identical to
// round 15.
// ---------------------------------------------------------------------------
__global__ __launch_bounds__(512, 2) void gemm256_pipe_kernel(
    const ushort* __restrict__ Ab, const ushort* __restrict__ Wt,
    float* __restrict__ out, int M, int N, int K)
{
    __shared__ ushort smem[4 * 16384];   // 4 slots x 32 KiB = 128 KiB

    const int bid = blockIdx.x;
    const int nwg = gridDim.x;
    int wg = bid;
    if ((nwg & 7) == 0) {                // bijective XCD swizzle
        const int cpx = nwg >> 3;
        wg = (bid & 7) * cpx + (bid >> 3);
    }
    const int ntn = N / BN;
    const int m0 = (wg / ntn) * BM;
    const int n0 = (wg % ntn) * BN;

    const int t    = threadIdx.x;
    const int lane = t & 63;
    const int w    = t >> 6;
    const int wm   = w >> 2;             // 2 (M) x 4 (N) wave grid
    const int wn   = w & 3;
    const int NT   = K / BK;

    // Staging: statement s covers rows s*128 + (t>>2); thread t stages the
    // 16B chunk j = (t&3) ^ ((row>>1)&3) of the row's 64B (pre-swizzled
    // global source, linear LDS destination).
    const ushort* pa[2]; const ushort* pb[2];
    int dstA[2], dstB[2];
#pragma unroll
    for (int s = 0; s < 2; ++s) {
        const int r = s * 128 + (t >> 2);
        const int j = (t & 3) ^ ((r >> 1) & 3);
        pa[s] = Ab + (size_t)(m0 + r) * K + j * 8;
        pb[s] = Wt + (size_t)(n0 + r) * K + j * 8;
        dstA[s] = s * 8192 + t * 16;            // byte offsets within slot
        dstB[s] = 16384 + s * 8192 + t * 16;
    }

    // Fragment read byte-offsets within a slot (swizzled read).
    int aoff[8], boff[4];
#pragma unroll
    for (int i = 0; i < 8; ++i) {
        const int r = wm * 128 + i * 16 + (lane & 15);
        aoff[i] = r * 64 + (((lane >> 4) ^ ((r >> 1) & 3)) << 4);
    }
#pragma unroll
    for (int j = 0; j < 4; ++j) {
        const int r = wn * 64 + j * 16 + (lane & 15);
        boff[j] = 16384 + r * 64 + (((lane >> 4) ^ ((r >> 1) & 3)) << 4);
    }

    floatx4 acc[8][4];
#pragma unroll
    for (int i = 0; i < 8; ++i)
#pragma unroll
        for (int j = 0; j < 4; ++j) acc[i][j] = floatx4{0.f, 0.f, 0.f, 0.f};

    short8 af[8], bf[4];                 // fragment registers, live across BAR

    auto stage = [&](int Td) __attribute__((always_inline)) {
        char* sd = (char*)smem + (Td & 3) * 32768;
        const int ko = Td * 32;
        GLOAD_LDS16(pa[0] + ko, sd + dstA[0]);
        GLOAD_LDS16(pa[1] + ko, sd + dstA[1]);
        GLOAD_LDS16(pb[0] + ko, sd + dstB[0]);
        GLOAD_LDS16(pb[1] + ko, sd + dstB[1]);
    };
    auto read_af03 = [&](int T) __attribute__((always_inline)) {
        const char* sb = (const char*)smem + (T & 3) * 32768;
#pragma unroll
        for (int i = 0; i < 4; ++i)
            af[i] = *reinterpret_cast<const short8*>(sb + aoff[i]);
    };
    auto read_rest = [&](int T) __attribute__((always_inline)) {
        const char* sb = (const char*)smem + (T & 3) * 32768;
#pragma unroll
        for (int i = 4; i < 8; ++i)
            af[i] = *reinterpret_cast<const short8*>(sb + aoff[i]);
#pragma unroll
        for (int j = 0; j < 4; ++j)
            bf[j] = *reinterpret_cast<const short8*>(sb + boff[j]);
    };
    auto read_all = [&](int T) __attribute__((always_inline)) {
        read_af03(T); read_rest(T);
    };
    auto mfma_rows = [&](int i0, int i1) __attribute__((always_inline)) {
        __builtin_amdgcn_s_setprio(1);
        for (int i = i0; i < i1; ++i)
#pragma unroll
            for (int j = 0; j < 4; ++j)
                acc[i][j] = __builtin_amdgcn_mfma_f32_16x16x32_bf16(af[i], bf[j], acc[i][j], 0, 0, 0);
        __builtin_amdgcn_s_setprio(0);
    };
    // note: mfma_rows called with literal bounds; unrolls fully.

    // Prologue: stage tiles 0,1,2; vmcnt(4) retires tiles 0 AND 1; barrier
    // globalizes; read frags(0) post-barrier (tile 0 proven globally).
    stage(0); stage(1); stage(2);
    VMCNT(4);
    BAR();
    read_all(0);

    for (int T = 0; T + 3 < NT; ++T) {
        LGKM0();                         // frags(T) arrived
        SCHEDB();                        // don't let MFMAs hoist above wait
        stage(T + 3);
        mfma_rows(0, 4);                 // rows 0-3 use af[0..3] (old)
        read_af03(T + 1);                // proven at entry; overlaps rows 4-7
        mfma_rows(4, 8);                 // rows 4-7 use af[4..7] (old)
        read_rest(T + 1);
        SCHEDB();
        VMCNT(4);                        // retires tile T+2 (globalized at BAR)
        BAR();
    }
    // T = NT-3: no stage; frags(NT-2) proven at entry (prev vmcnt(4)).
    LGKM0(); SCHEDB();
    mfma_rows(0, 4); read_af03(NT - 2);
    mfma_rows(4, 8); read_rest(NT - 2);
    SCHEDB(); VMCNT(0); BAR();           // proves NT-1 for next window
    // T = NT-2: frags(NT-1) proven at entry; no more LDS writes -> no BAR.
    LGKM0(); SCHEDB();
    mfma_rows(0, 4); read_af03(NT - 1);
    mfma_rows(4, 8); read_rest(NT - 1);
    // T = NT-1
    LGKM0(); SCHEDB();
    mfma_rows(0, 4); mfma_rows(4, 8);

    // Epilogue: D col = lane&15, row = 4*(lane>>4)+reg  (fp32 out)
    const int orow0 = m0 + wm * 128 + (lane >> 4) * 4;
    const int ocol0 = n0 + wn * 64 + (lane & 15);
#pragma unroll
    for (int i = 0; i < 8; ++i)
#pragma unroll
        for (int j = 0; j < 4; ++j)
#pragma unroll
            for (int r = 0; r < 4; ++r)
                out[(size_t)(orow0 + i * 16 + r) * N + ocol0 + j * 16] = acc[i][j][r];
}

// ---------------------------------------------------------------------------
// Last-resort naive VALU path (no workspace / odd shapes): correct, slow.
// ---------------------------------------------------------------------------
#define MR 16
__global__ __launch_bounds__(256) void naive_kernel(
    const float* __restrict__ x, const int* __restrict__ q,
    const float* __restrict__ sc, float* __restrict__ out,
    int M, int N, int K)
{
    const int n  = blockIdx.x * 256 + threadIdx.x;
    const int m0 = blockIdx.y * MR;
    float acc[MR];
#pragma unroll
    for (int i = 0; i < MR; ++i) acc[i] = 0.f;
    for (int k = 0; k < K; ++k) {
        const float s = sc[(size_t)(k / GROUP) * N + n];
        const float w = (float)(q[(size_t)k * N + n] - ZP) * s;
#pragma unroll
        for (int i = 0; i < MR; ++i)
            acc[i] = fmaf(x[(size_t)(m0 + i) * K + k], w, acc[i]);
    }
#pragma unroll
    for (int i = 0; i < MR; ++i)
        out[(size_t)(m0 + i) * N + n] = acc[i];
}

extern "C" void kernel_launch(void* const* d_in, const int* in_sizes, int n_in,
                              void* d_out, int out_size, void* d_ws, size_t ws_size,
                              hipStream_t stream) {
    const float* x  = (const float*)d_in[0];
    const int*   q  = (const int*)d_in[1];
    const float* sc = (const float*)d_in[2];
    float*       o  = (float*)d_out;

    int M = 8192, K = 4096, N = 4096;
    if (!((long long)in_sizes[0] == (long long)M * K &&
          (long long)in_sizes[1] == (long long)K * N &&
          (long long)out_size    == (long long)M * N)) {
        const double S0 = (double)in_sizes[0], S1 = (double)in_sizes[1];
        K = (int)llround(sqrt(S0 * S1 / (double)out_size));
        N = in_sizes[1] / K;
        M = in_sizes[0] / K;
    }

    const size_t xb_bytes = (size_t)M * K * 2;
    const size_t wt_bytes = (size_t)N * K * 2;

    const bool ok = (M % BM == 0) && (N % BN == 0) && (K % BK == 0) &&
                    (K / BK >= 5) && (N % 64 == 0) && (K % 64 == 0) &&
                    (K % GROUP == 0) && (ws_size >= xb_bytes + wt_bytes);

    if (ok) {
        ushort* xb = (ushort*)d_ws;
        ushort* wt = (ushort*)((char*)d_ws + xb_bytes);
        const int ndeq = (K / 64) * (N / 64);
        prep_kernel<<<dim3(ndeq + 2048), 256, 0, stream>>>(
            x, q, sc, xb, wt, K, N, (size_t)M * K / 8, ndeq);
        const int ngemm = (M / BM) * (N / BN);
        gemm256_pipe_kernel<<<dim3(ngemm), 512, 0, stream>>>(xb, wt, o, M, N, K);
    } else {
        naive_kernel<<<dim3(N / 256, M / MR), 256, 0, stream>>>(x, q, sc, o, M, N, K);
    }
}

// Round 18
// 284.541 us; speedup vs baseline: 1.4951x; 1.0003x over previous
//
#include <hip/hip_runtime.h>
#include <stdint.h>
#include <math.h>

#define GROUP 128
#define ZP 8
#define BM 256
#define BN 256
#define BK 32

typedef short short8 __attribute__((ext_vector_type(8)));   // 8 x bf16 bits
typedef float floatx4 __attribute__((ext_vector_type(4)));

typedef __attribute__((address_space(3))) void lds_void;
typedef const __attribute__((address_space(1))) void gbl_void;
#define GLOAD_LDS16(g, l) \
  __builtin_amdgcn_global_load_lds((gbl_void*)(g), (lds_void*)(l), 16, 0, 0)

#define VMCNT(n) asm volatile("s_waitcnt vmcnt(" #n ")" ::: "memory")
#define LGKM0()  asm volatile("s_waitcnt lgkmcnt(0)" ::: "memory")
#define BAR()    __builtin_amdgcn_s_barrier()
#define SCHEDB() __builtin_amdgcn_sched_barrier(0)

__device__ __forceinline__ ushort f2bf(float f) {  // round-to-nearest-even
    union { float f; uint32_t i; } v; v.f = f;
    uint32_t r = v.i + 0x7FFF + ((v.i >> 16) & 1);
    return (ushort)(r >> 16);
}

// ---------------------------------------------------------------------------
// Merged prepass (both memory-bound; one launch):
//   blocks [0, ndeq):        dequant+transpose  wt[n][k] = bf16((q-8)*s)
//   blocks [ndeq, gridDim):  x fp32 -> bf16 (grid-stride, 8 elems/thread)
// ---------------------------------------------------------------------------
__global__ __launch_bounds__(256) void prep_kernel(
    const float* __restrict__ x, const int* __restrict__ q,
    const float* __restrict__ scale, ushort* __restrict__ xb,
    ushort* __restrict__ wt, int K, int N, size_t total8, int ndeq)
{
    __shared__ ushort T[64 * 68];
    const int t = threadIdx.x;

    if ((int)blockIdx.x < ndeq) {
        const int ktiles = K / 64;
        const int k0 = (blockIdx.x % ktiles) * 64;
        const int n0 = (blockIdx.x / ktiles) * 64;
        const int g  = k0 / GROUP;
        const int c  = (t & 15) * 4;
        const int r0 = (t >> 4);

        const float4 s = *reinterpret_cast<const float4*>(&scale[(size_t)g * N + n0 + c]);

#pragma unroll
        for (int j = 0; j < 4; ++j) {
            const int r = r0 + j * 16;
            const int4 qv = *reinterpret_cast<const int4*>(&q[(size_t)(k0 + r) * N + n0 + c]);
            T[(c + 0) * 68 + r] = f2bf((float)(qv.x - ZP) * s.x);
            T[(c + 1) * 68 + r] = f2bf((float)(qv.y - ZP) * s.y);
            T[(c + 2) * 68 + r] = f2bf((float)(qv.z - ZP) * s.z);
            T[(c + 3) * 68 + r] = f2bf((float)(qv.w - ZP) * s.w);
        }
        __syncthreads();
#pragma unroll
        for (int j = 0; j < 4; ++j) {
            const int nn = r0 + j * 16;
            const int kk = c;
            const uint2 v = *reinterpret_cast<const uint2*>(&T[nn * 68 + kk]);
            *reinterpret_cast<uint2*>(&wt[(size_t)(n0 + nn) * K + k0 + kk]) = v;
        }
    } else {
        const size_t nblk   = (size_t)(gridDim.x - ndeq);
        const size_t stride = nblk * 256;
        for (size_t id = (size_t)(blockIdx.x - ndeq) * 256 + t; id < total8; id += stride) {
            const float4 a = *reinterpret_cast<const float4*>(x + id * 8);
            const float4 b = *reinterpret_cast<const float4*>(x + id * 8 + 4);
            ushort o[8] __attribute__((aligned(16)));
            o[0] = f2bf(a.x); o[1] = f2bf(a.y); o[2] = f2bf(a.z); o[3] = f2bf(a.w);
            o[4] = f2bf(b.x); o[5] = f2bf(b.y); o[6] = f2bf(b.z); o[7] = f2bf(b.w);
            *reinterpret_cast<uint4*>(xb + id * 8) = *reinterpret_cast<const uint4*>(o);
        }
    }
}

// ---------------------------------------------------------------------------
// GEMM: A bf16 [M][K] x Wt bf16 [N][K] -> out fp32 [M][N]
// 256x256 tile, BK=32, 8 waves (2Mx4N), per-wave 128x64 (acc 8x4 frags),
// 16x16x32 MFMA, round-7-validated swizzle (0 conflicts).
// Round-15 vmcnt(4) ledger (tile T+1 proven globally at window-T ENTRY
// barrier) + round-16 mid-window read placement: af[0..3](T+1) read between
// the MFMA half-bursts (overlaps rows 4-7 issue), af[4..7]+bf AFTER rows
// 4-7 (bf(T) must stay live through them), before the vmcnt asm.
// VALIDATED at 284.6 us total / 235-237 us GEMM, MfmaUtil 53%.
// ---------------------------------------------------------------------------
__global__ __launch_bounds__(512, 2) void gemm256_pipe_kernel(
    const ushort* __restrict__ Ab, const ushort* __restrict__ Wt,
    float* __restrict__ out, int M, int N, int K)
{
    __shared__ ushort smem[4 * 16384];   // 4 slots x 32 KiB = 128 KiB

    const int bid = blockIdx.x;
    const int nwg = gridDim.x;
    int wg = bid;
    if ((nwg & 7) == 0) {                // bijective XCD swizzle
        const int cpx = nwg >> 3;
        wg = (bid & 7) * cpx + (bid >> 3);
    }
    const int ntn = N / BN;
    const int m0 = (wg / ntn) * BM;
    const int n0 = (wg % ntn) * BN;

    const int t    = threadIdx.x;
    const int lane = t & 63;
    const int w    = t >> 6;
    const int wm   = w >> 2;             // 2 (M) x 4 (N) wave grid
    const int wn   = w & 3;
    const int NT   = K / BK;

    // Staging: statement s covers rows s*128 + (t>>2); thread t stages the
    // 16B chunk j = (t&3) ^ ((row>>1)&3) of the row's 64B (pre-swizzled
    // global source, linear LDS destination).
    const ushort* pa[2]; const ushort* pb[2];
    int dstA[2], dstB[2];
#pragma unroll
    for (int s = 0; s < 2; ++s) {
        const int r = s * 128 + (t >> 2);
        const int j = (t & 3) ^ ((r >> 1) & 3);
        pa[s] = Ab + (size_t)(m0 + r) * K + j * 8;
        pb[s] = Wt + (size_t)(n0 + r) * K + j * 8;
        dstA[s] = s * 8192 + t * 16;            // byte offsets within slot
        dstB[s] = 16384 + s * 8192 + t * 16;
    }

    // Fragment read byte-offsets within a slot (swizzled read).
    int aoff[8], boff[4];
#pragma unroll
    for (int i = 0; i < 8; ++i) {
        const int r = wm * 128 + i * 16 + (lane & 15);
        aoff[i] = r * 64 + (((lane >> 4) ^ ((r >> 1) & 3)) << 4);
    }
#pragma unroll
    for (int j = 0; j < 4; ++j) {
        const int r = wn * 64 + j * 16 + (lane & 15);
        boff[j] = 16384 + r * 64 + (((lane >> 4) ^ ((r >> 1) & 3)) << 4);
    }

    floatx4 acc[8][4];
#pragma unroll
    for (int i = 0; i < 8; ++i)
#pragma unroll
        for (int j = 0; j < 4; ++j) acc[i][j] = floatx4{0.f, 0.f, 0.f, 0.f};

    short8 af[8], bf[4];                 // fragment registers, live across BAR

    auto stage = [&](int Td) __attribute__((always_inline)) {
        char* sd = (char*)smem + (Td & 3) * 32768;
        const int ko = Td * 32;
        GLOAD_LDS16(pa[0] + ko, sd + dstA[0]);
        GLOAD_LDS16(pa[1] + ko, sd + dstA[1]);
        GLOAD_LDS16(pb[0] + ko, sd + dstB[0]);
        GLOAD_LDS16(pb[1] + ko, sd + dstB[1]);
    };
    auto read_af03 = [&](int T) __attribute__((always_inline)) {
        const char* sb = (const char*)smem + (T & 3) * 32768;
#pragma unroll
        for (int i = 0; i < 4; ++i)
            af[i] = *reinterpret_cast<const short8*>(sb + aoff[i]);
    };
    auto read_rest = [&](int T) __attribute__((always_inline)) {
        const char* sb = (const char*)smem + (T & 3) * 32768;
#pragma unroll
        for (int i = 4; i < 8; ++i)
            af[i] = *reinterpret_cast<const short8*>(sb + aoff[i]);
#pragma unroll
        for (int j = 0; j < 4; ++j)
            bf[j] = *reinterpret_cast<const short8*>(sb + boff[j]);
    };
    auto read_all = [&](int T) __attribute__((always_inline)) {
        read_af03(T); read_rest(T);
    };
    auto mfma_rows = [&](int i0, int i1) __attribute__((always_inline)) {
        __builtin_amdgcn_s_setprio(1);
        for (int i = i0; i < i1; ++i)
#pragma unroll
            for (int j = 0; j < 4; ++j)
                acc[i][j] = __builtin_amdgcn_mfma_f32_16x16x32_bf16(af[i], bf[j], acc[i][j], 0, 0, 0);
        __builtin_amdgcn_s_setprio(0);
    };

    // Prologue: stage tiles 0,1,2; vmcnt(4) retires tiles 0 AND 1; barrier
    // globalizes; read frags(0) post-barrier (tile 0 proven globally).
    stage(0); stage(1); stage(2);
    VMCNT(4);
    BAR();
    read_all(0);

    for (int T = 0; T + 3 < NT; ++T) {
        LGKM0();                         // frags(T) arrived
        SCHEDB();                        // don't let MFMAs hoist above wait
        stage(T + 3);
        mfma_rows(0, 4);                 // rows 0-3 use af[0..3] (old)
        read_af03(T + 1);                // proven at entry; overlaps rows 4-7
        mfma_rows(4, 8);                 // rows 4-7 use af[4..7] + bf (old)
        read_rest(T + 1);
        SCHEDB();
        VMCNT(4);                        // retires tile T+2 (globalized at BAR)
        BAR();
    }
    // T = NT-3: no stage; frags(NT-2) proven at entry (prev vmcnt(4)).
    LGKM0(); SCHEDB();
    mfma_rows(0, 4); read_af03(NT - 2);
    mfma_rows(4, 8); read_rest(NT - 2);
    SCHEDB(); VMCNT(0); BAR();           // proves NT-1 for next window
    // T = NT-2: tile NT-1 proven at entry; no more LDS writes -> no BAR.
    LGKM0(); SCHEDB();
    mfma_rows(0, 4); read_af03(NT - 1);
    mfma_rows(4, 8); read_rest(NT - 1);
    // T = NT-1
    LGKM0(); SCHEDB();
    mfma_rows(0, 4); mfma_rows(4, 8);

    // Epilogue: D col = lane&15, row = 4*(lane>>4)+reg  (fp32 out)
    const int orow0 = m0 + wm * 128 + (lane >> 4) * 4;
    const int ocol0 = n0 + wn * 64 + (lane & 15);
#pragma unroll
    for (int i = 0; i < 8; ++i)
#pragma unroll
        for (int j = 0; j < 4; ++j)
#pragma unroll
            for (int r = 0; r < 4; ++r)
                out[(size_t)(orow0 + i * 16 + r) * N + ocol0 + j * 16] = acc[i][j][r];
}

// ---------------------------------------------------------------------------
// Last-resort naive VALU path (no workspace / odd shapes): correct, slow.
// ---------------------------------------------------------------------------
#define MR 16
__global__ __launch_bounds__(256) void naive_kernel(
    const float* __restrict__ x, const int* __restrict__ q,
    const float* __restrict__ sc, float* __restrict__ out,
    int M, int N, int K)
{
    const int n  = blockIdx.x * 256 + threadIdx.x;
    const int m0 = blockIdx.y * MR;
    float acc[MR];
#pragma unroll
    for (int i = 0; i < MR; ++i) acc[i] = 0.f;
    for (int k = 0; k < K; ++k) {
        const float s = sc[(size_t)(k / GROUP) * N + n];
        const float w = (float)(q[(size_t)k * N + n] - ZP) * s;
#pragma unroll
        for (int i = 0; i < MR; ++i)
            acc[i] = fmaf(x[(size_t)(m0 + i) * K + k], w, acc[i]);
    }
#pragma unroll
    for (int i = 0; i < MR; ++i)
        out[(size_t)(m0 + i) * N + n] = acc[i];
}

extern "C" void kernel_launch(void* const* d_in, const int* in_sizes, int n_in,
                              void* d_out, int out_size, void* d_ws, size_t ws_size,
                              hipStream_t stream) {
    const float* x  = (const float*)d_in[0];
    const int*   q  = (const int*)d_in[1];
    const float* sc = (const float*)d_in[2];
    float*       o  = (float*)d_out;

    int M = 8192, K = 4096, N = 4096;
    if (!((long long)in_sizes[0] == (long long)M * K &&
          (long long)in_sizes[1] == (long long)K * N &&
          (long long)out_size    == (long long)M * N)) {
        const double S0 = (double)in_sizes[0], S1 = (double)in_sizes[1];
        K = (int)llround(sqrt(S0 * S1 / (double)out_size));
        N = in_sizes[1] / K;
        M = in_sizes[0] / K;
    }

    const size_t xb_bytes = (size_t)M * K * 2;
    const size_t wt_bytes = (size_t)N * K * 2;

    const bool ok = (M % BM == 0) && (N % BN == 0) && (K % BK == 0) &&
                    (K / BK >= 5) && (N % 64 == 0) && (K % 64 == 0) &&
                    (K % GROUP == 0) && (ws_size >= xb_bytes + wt_bytes);

    if (ok) {
        ushort* xb = (ushort*)d_ws;
        ushort* wt = (ushort*)((char*)d_ws + xb_bytes);
        const int ndeq = (K / 64) * (N / 64);
        prep_kernel<<<dim3(ndeq + 2048), 256, 0, stream>>>(
            x, q, sc, xb, wt, K, N, (size_t)M * K / 8, ndeq);
        const int ngemm = (M / BM) * (N / BN);
        gemm256_pipe_kernel<<<dim3(ngemm), 512, 0, stream>>>(xb, wt, o, M, N, K);
    } else {
        naive_kernel<<<dim3(N / 256, M / MR), 256, 0, stream>>>(x, q, sc, o, M, N, K);
    }
}

// Round 19
// 284.141 us; speedup vs baseline: 1.4972x; 1.0014x over previous
//
#include <hip/hip_runtime.h>
#include <stdint.h>
#include <math.h>

#define GROUP 128
#define ZP 8
#define BM 256
#define BN 256
#define BK 32

typedef short short8 __attribute__((ext_vector_type(8)));   // 8 x bf16 bits
typedef float floatx4 __attribute__((ext_vector_type(4)));

typedef __attribute__((address_space(3))) void lds_void;
typedef const __attribute__((address_space(1))) void gbl_void;
#define GLOAD_LDS16(g, l) \
  __builtin_amdgcn_global_load_lds((gbl_void*)(g), (lds_void*)(l), 16, 0, 0)

#define VMCNT(n) asm volatile("s_waitcnt vmcnt(" #n ")" ::: "memory")
#define LGKM0()  asm volatile("s_waitcnt lgkmcnt(0)" ::: "memory")
#define BAR()    __builtin_amdgcn_s_barrier()
#define SCHEDB() __builtin_amdgcn_sched_barrier(0)

__device__ __forceinline__ ushort f2bf(float f) {  // round-to-nearest-even
    union { float f; uint32_t i; } v; v.f = f;
    uint32_t r = v.i + 0x7FFF + ((v.i >> 16) & 1);
    return (ushort)(r >> 16);
}

// ---------------------------------------------------------------------------
// Merged prepass (both memory-bound; one launch):
//   blocks [0, ndeq):        dequant+transpose  wt[n][k] = bf16((q-8)*s)
//   blocks [ndeq, gridDim):  x fp32 -> bf16 (grid-stride, 8 elems/thread)
// ---------------------------------------------------------------------------
__global__ __launch_bounds__(256) void prep_kernel(
    const float* __restrict__ x, const int* __restrict__ q,
    const float* __restrict__ scale, ushort* __restrict__ xb,
    ushort* __restrict__ wt, int K, int N, size_t total8, int ndeq)
{
    __shared__ ushort T[64 * 68];
    const int t = threadIdx.x;

    if ((int)blockIdx.x < ndeq) {
        const int ktiles = K / 64;
        const int k0 = (blockIdx.x % ktiles) * 64;
        const int n0 = (blockIdx.x / ktiles) * 64;
        const int g  = k0 / GROUP;
        const int c  = (t & 15) * 4;
        const int r0 = (t >> 4);

        const float4 s = *reinterpret_cast<const float4*>(&scale[(size_t)g * N + n0 + c]);

#pragma unroll
        for (int j = 0; j < 4; ++j) {
            const int r = r0 + j * 16;
            const int4 qv = *reinterpret_cast<const int4*>(&q[(size_t)(k0 + r) * N + n0 + c]);
            T[(c + 0) * 68 + r] = f2bf((float)(qv.x - ZP) * s.x);
            T[(c + 1) * 68 + r] = f2bf((float)(qv.y - ZP) * s.y);
            T[(c + 2) * 68 + r] = f2bf((float)(qv.z - ZP) * s.z);
            T[(c + 3) * 68 + r] = f2bf((float)(qv.w - ZP) * s.w);
        }
        __syncthreads();
#pragma unroll
        for (int j = 0; j < 4; ++j) {
            const int nn = r0 + j * 16;
            const int kk = c;
            const uint2 v = *reinterpret_cast<const uint2*>(&T[nn * 68 + kk]);
            *reinterpret_cast<uint2*>(&wt[(size_t)(n0 + nn) * K + k0 + kk]) = v;
        }
    } else {
        const size_t nblk   = (size_t)(gridDim.x - ndeq);
        const size_t stride = nblk * 256;
        for (size_t id = (size_t)(blockIdx.x - ndeq) * 256 + t; id < total8; id += stride) {
            const float4 a = *reinterpret_cast<const float4*>(x + id * 8);
            const float4 b = *reinterpret_cast<const float4*>(x + id * 8 + 4);
            ushort o[8] __attribute__((aligned(16)));
            o[0] = f2bf(a.x); o[1] = f2bf(a.y); o[2] = f2bf(a.z); o[3] = f2bf(a.w);
            o[4] = f2bf(b.x); o[5] = f2bf(b.y); o[6] = f2bf(b.z); o[7] = f2bf(b.w);
            *reinterpret_cast<uint4*>(xb + id * 8) = *reinterpret_cast<const uint4*>(o);
        }
    }
}

// ---------------------------------------------------------------------------
// GEMM: A bf16 [M][K] x Wt bf16 [N][K] -> out fp32 [M][N]
// 256x256 tile, BK=32, 8 waves (2Mx4N), per-wave 128x64 (acc 8x4 frags),
// 16x16x32 MFMA, validated swizzle (0 conflicts), round-15 vmcnt(4) ledger
// (tile T+1 proven globally at window-T ENTRY barrier).
// NEW: per-row af refill. After row i's MFMAs, af[i](T) is dead -> read
// af[i](T+1) immediately (rows 4-7). Boundary late-reads drop 8->4/wave
// (bf only), halving the block-wide read pile-up that the next window's
// lgkmcnt(0) must drain. Register-liveness-safe by construction: each
// af[i](T+1) read is program-ordered after af[i](T)'s last use (SSA
// renaming keeps it correct even if hoisted). Sync structure unchanged.
// ---------------------------------------------------------------------------
__global__ __launch_bounds__(512, 2) void gemm256_pipe_kernel(
    const ushort* __restrict__ Ab, const ushort* __restrict__ Wt,
    float* __restrict__ out, int M, int N, int K)
{
    __shared__ ushort smem[4 * 16384];   // 4 slots x 32 KiB = 128 KiB

    const int bid = blockIdx.x;
    const int nwg = gridDim.x;
    int wg = bid;
    if ((nwg & 7) == 0) {                // bijective XCD swizzle
        const int cpx = nwg >> 3;
        wg = (bid & 7) * cpx + (bid >> 3);
    }
    const int ntn = N / BN;
    const int m0 = (wg / ntn) * BM;
    const int n0 = (wg % ntn) * BN;

    const int t    = threadIdx.x;
    const int lane = t & 63;
    const int w    = t >> 6;
    const int wm   = w >> 2;             // 2 (M) x 4 (N) wave grid
    const int wn   = w & 3;
    const int NT   = K / BK;

    // Staging: statement s covers rows s*128 + (t>>2); thread t stages the
    // 16B chunk j = (t&3) ^ ((row>>1)&3) of the row's 64B (pre-swizzled
    // global source, linear LDS destination).
    const ushort* pa[2]; const ushort* pb[2];
    int dstA[2], dstB[2];
#pragma unroll
    for (int s = 0; s < 2; ++s) {
        const int r = s * 128 + (t >> 2);
        const int j = (t & 3) ^ ((r >> 1) & 3);
        pa[s] = Ab + (size_t)(m0 + r) * K + j * 8;
        pb[s] = Wt + (size_t)(n0 + r) * K + j * 8;
        dstA[s] = s * 8192 + t * 16;            // byte offsets within slot
        dstB[s] = 16384 + s * 8192 + t * 16;
    }

    // Fragment read byte-offsets within a slot (swizzled read).
    int aoff[8], boff[4];
#pragma unroll
    for (int i = 0; i < 8; ++i) {
        const int r = wm * 128 + i * 16 + (lane & 15);
        aoff[i] = r * 64 + (((lane >> 4) ^ ((r >> 1) & 3)) << 4);
    }
#pragma unroll
    for (int j = 0; j < 4; ++j) {
        const int r = wn * 64 + j * 16 + (lane & 15);
        boff[j] = 16384 + r * 64 + (((lane >> 4) ^ ((r >> 1) & 3)) << 4);
    }

    floatx4 acc[8][4];
#pragma unroll
    for (int i = 0; i < 8; ++i)
#pragma unroll
        for (int j = 0; j < 4; ++j) acc[i][j] = floatx4{0.f, 0.f, 0.f, 0.f};

    short8 af[8], bf[4];                 // fragment registers, live across BAR

    auto stage = [&](int Td) __attribute__((always_inline)) {
        char* sd = (char*)smem + (Td & 3) * 32768;
        const int ko = Td * 32;
        GLOAD_LDS16(pa[0] + ko, sd + dstA[0]);
        GLOAD_LDS16(pa[1] + ko, sd + dstA[1]);
        GLOAD_LDS16(pb[0] + ko, sd + dstB[0]);
        GLOAD_LDS16(pb[1] + ko, sd + dstB[1]);
    };
    auto read_af03 = [&](int T) __attribute__((always_inline)) {
        const char* sb = (const char*)smem + (T & 3) * 32768;
#pragma unroll
        for (int i = 0; i < 4; ++i)
            af[i] = *reinterpret_cast<const short8*>(sb + aoff[i]);
    };
    auto read_af47 = [&](int T) __attribute__((always_inline)) {
        const char* sb = (const char*)smem + (T & 3) * 32768;
#pragma unroll
        for (int i = 4; i < 8; ++i)
            af[i] = *reinterpret_cast<const short8*>(sb + aoff[i]);
    };
    auto read_bf4 = [&](int T) __attribute__((always_inline)) {
        const char* sb = (const char*)smem + (T & 3) * 32768;
#pragma unroll
        for (int j = 0; j < 4; ++j)
            bf[j] = *reinterpret_cast<const short8*>(sb + boff[j]);
    };
    auto mfma_rows03 = [&]() __attribute__((always_inline)) {
        __builtin_amdgcn_s_setprio(1);
#pragma unroll
        for (int i = 0; i < 4; ++i)
#pragma unroll
            for (int j = 0; j < 4; ++j)
                acc[i][j] = __builtin_amdgcn_mfma_f32_16x16x32_bf16(af[i], bf[j], acc[i][j], 0, 0, 0);
        __builtin_amdgcn_s_setprio(0);
    };
    // Rows 4-7 with per-row af refill from tile Tn (when doread).
    auto mfma_rows47_read = [&](int Tn, bool doread) __attribute__((always_inline)) {
        const char* sn = (const char*)smem + (Tn & 3) * 32768;
        __builtin_amdgcn_s_setprio(1);
#pragma unroll
        for (int i = 4; i < 8; ++i) {
#pragma unroll
            for (int j = 0; j < 4; ++j)
                acc[i][j] = __builtin_amdgcn_mfma_f32_16x16x32_bf16(af[i], bf[j], acc[i][j], 0, 0, 0);
            if (doread)
                af[i] = *reinterpret_cast<const short8*>(sn + aoff[i]);
        }
        __builtin_amdgcn_s_setprio(0);
    };

    // Prologue: stage tiles 0,1,2; vmcnt(4) retires tiles 0 AND 1; barrier
    // globalizes; read frags(0) post-barrier (tile 0 proven globally).
    stage(0); stage(1); stage(2);
    VMCNT(4);
    BAR();
    read_af03(0); read_af47(0); read_bf4(0);

    for (int T = 0; T + 3 < NT; ++T) {
        LGKM0();                         // frags(T) arrived
        SCHEDB();                        // don't let MFMAs hoist above wait
        stage(T + 3);
        mfma_rows03();                   // rows 0-3: af[0..3](T) + bf(T)
        read_af03(T + 1);                // af[0..3] dead -> refill (proven at entry)
        mfma_rows47_read(T + 1, true);   // rows 4-7 with per-row af refill
        read_bf4(T + 1);                 // only 4 reads left at the boundary
        SCHEDB();
        VMCNT(4);                        // retires tile T+2 (globalized at BAR)
        BAR();
    }
    // T = NT-3: no stage; frags(NT-2) proven at entry (prev vmcnt(4)).
    LGKM0(); SCHEDB();
    mfma_rows03(); read_af03(NT - 2);
    mfma_rows47_read(NT - 2, true); read_bf4(NT - 2);
    SCHEDB(); VMCNT(0); BAR();           // proves NT-1 for next window
    // T = NT-2: tile NT-1 proven at entry; no more LDS writes -> no BAR.
    LGKM0(); SCHEDB();
    mfma_rows03(); read_af03(NT - 1);
    mfma_rows47_read(NT - 1, true); read_bf4(NT - 1);
    // T = NT-1
    LGKM0(); SCHEDB();
    mfma_rows03(); mfma_rows47_read(0, false);

    // Epilogue: D col = lane&15, row = 4*(lane>>4)+reg  (fp32 out)
    const int orow0 = m0 + wm * 128 + (lane >> 4) * 4;
    const int ocol0 = n0 + wn * 64 + (lane & 15);
#pragma unroll
    for (int i = 0; i < 8; ++i)
#pragma unroll
        for (int j = 0; j < 4; ++j)
#pragma unroll
            for (int r = 0; r < 4; ++r)
                out[(size_t)(orow0 + i * 16 + r) * N + ocol0 + j * 16] = acc[i][j][r];
}

// ---------------------------------------------------------------------------
// Last-resort naive VALU path (no workspace / odd shapes): correct, slow.
// ---------------------------------------------------------------------------
#define MR 16
__global__ __launch_bounds__(256) void naive_kernel(
    const float* __restrict__ x, const int* __restrict__ q,
    const float* __restrict__ sc, float* __restrict__ out,
    int M, int N, int K)
{
    const int n  = blockIdx.x * 256 + threadIdx.x;
    const int m0 = blockIdx.y * MR;
    float acc[MR];
#pragma unroll
    for (int i = 0; i < MR; ++i) acc[i] = 0.f;
    for (int k = 0; k < K; ++k) {
        const float s = sc[(size_t)(k / GROUP) * N + n];
        const float w = (float)(q[(size_t)k * N + n] - ZP) * s;
#pragma unroll
        for (int i = 0; i < MR; ++i)
            acc[i] = fmaf(x[(size_t)(m0 + i) * K + k], w, acc[i]);
    }
#pragma unroll
    for (int i = 0; i < MR; ++i)
        out[(size_t)(m0 + i) * N + n] = acc[i];
}

extern "C" void kernel_launch(void* const* d_in, const int* in_sizes, int n_in,
                              void* d_out, int out_size, void* d_ws, size_t ws_size,
                              hipStream_t stream) {
    const float* x  = (const float*)d_in[0];
    const int*   q  = (const int*)d_in[1];
    const float* sc = (const float*)d_in[2];
    float*       o  = (float*)d_out;

    int M = 8192, K = 4096, N = 4096;
    if (!((long long)in_sizes[0] == (long long)M * K &&
          (long long)in_sizes[1] == (long long)K * N &&
          (long long)out_size    == (long long)M * N)) {
        const double S0 = (double)in_sizes[0], S1 = (double)in_sizes[1];
        K = (int)llround(sqrt(S0 * S1 / (double)out_size));
        N = in_sizes[1] / K;
        M = in_sizes[0] / K;
    }

    const size_t xb_bytes = (size_t)M * K * 2;
    const size_t wt_bytes = (size_t)N * K * 2;

    const bool ok = (M % BM == 0) && (N % BN == 0) && (K % BK == 0) &&
                    (K / BK >= 5) && (N % 64 == 0) && (K % 64 == 0) &&
                    (K % GROUP == 0) && (ws_size >= xb_bytes + wt_bytes);

    if (ok) {
        ushort* xb = (ushort*)d_ws;
        ushort* wt = (ushort*)((char*)d_ws + xb_bytes);
        const int ndeq = (K / 64) * (N / 64);
        prep_kernel<<<dim3(ndeq + 2048), 256, 0, stream>>>(
            x, q, sc, xb, wt, K, N, (size_t)M * K / 8, ndeq);
        const int ngemm = (M / BM) * (N / BN);
        gemm256_pipe_kernel<<<dim3(ngemm), 512, 0, stream>>>(xb, wt, o, M, N, K);
    } else {
        naive_kernel<<<dim3(N / 256, M / MR), 256, 0, stream>>>(x, q, sc, o, M, N, K);
    }
}